// Round 1
// 275.461 us; speedup vs baseline: 1.0104x; 1.0104x over previous
//
#include <hip/hip_runtime.h>
#include <stdint.h>

// GAT layer, B=8, N=2048, D=128, fp32 in/out.
// Kernel A (fc): h = (x*mask)@W -> hT bf16 [B][D][N] (transposed), e_l, e_r.
// Kernel B (attn): 4-wave split-j flash attention per 16-row tile.
//   Each wave runs the wave-self-contained flash loop over 1/4 of the
//   j-range (no LDS, no barriers inside the loop); partial (m,l,acc) are
//   merged through LDS (online-softmax combine); 256-thread epilogue does
//   residual + LayerNorm with coalesced float4 I/O.

#define BB 8
#define NN 2048
#define DD 128
#define GAT_NEG_INF -10000.0f
#define LN_EPS 1e-5f

typedef __attribute__((ext_vector_type(8))) short short8;
typedef __attribute__((ext_vector_type(4))) float f32x4;

__device__ __forceinline__ unsigned pk_bf16(float a, float b) {
    // RTN-even fp32->bf16 pack (inputs finite)
    unsigned ua = __float_as_uint(a); ua += 0x7FFFu + ((ua >> 16) & 1u);
    unsigned ub = __float_as_uint(b); ub += 0x7FFFu + ((ub >> 16) & 1u);
    return (ua >> 16) | (ub & 0xFFFF0000u);
}

// ---------------------------------------------------------------------------
// Kernel A: grid = BB*(NN/32) = 512, block = 256.
// 32 rows of h per block; thread (r=t>>3, c=t&7) owns row r, cols c*16..+15.
// Epilogue stages the 128x32 transposed tile through LDS and stores bf16 hT.
// ---------------------------------------------------------------------------
__global__ __launch_bounds__(256) void fc_kernel(
    const float* __restrict__ x, const int* __restrict__ mask,
    const float* __restrict__ W, const float* __restrict__ a_l,
    const float* __restrict__ a_r, unsigned short* __restrict__ hT,
    float* __restrict__ el, float* __restrict__ er)
{
    __shared__ __align__(16) float Ws[64 * DD];   // 32 KB; reused as hTs[128][33]
    __shared__ __align__(16) float xs[32 * 68];

    const int t  = threadIdx.x;
    const int b  = blockIdx.x >> 6;
    const int it = blockIdx.x & 63;
    const int i0 = it * 32;

    const int r  = t >> 3;   // 0..31
    const int c  = t & 7;    // 0..7
    const int o0 = c * 16;

    float acc[16];
#pragma unroll
    for (int u = 0; u < 16; ++u) acc[u] = 0.f;

    for (int kt = 0; kt < 2; ++kt) {
        __syncthreads();
        const float4* W4  = (const float4*)(W + (size_t)kt * 64 * DD);
        float4*       Ws4 = (float4*)Ws;
#pragma unroll
        for (int i = 0; i < 8; ++i) Ws4[t + 256 * i] = W4[t + 256 * i];
#pragma unroll
        for (int i = 0; i < 2; ++i) {
            int idx = t + 256 * i;
            int row = idx >> 4, c4 = idx & 15;
            float4 v = *(const float4*)(x + ((size_t)(b * NN + i0 + row)) * DD
                                          + kt * 64 + c4 * 4);
            float mm = (float)mask[b * NN + i0 + row];
            v.x *= mm; v.y *= mm; v.z *= mm; v.w *= mm;
            *(float4*)(xs + row * 68 + c4 * 4) = v;
        }
        __syncthreads();

        const float4* Wsr = (const float4*)Ws;
#pragma unroll 4
        for (int k = 0; k < 64; ++k) {
            float xv = xs[r * 68 + k];
#pragma unroll
            for (int u4 = 0; u4 < 4; ++u4) {
                float4 w = Wsr[k * 32 + c * 4 + u4];
                acc[u4 * 4 + 0] += xv * w.x;
                acc[u4 * 4 + 1] += xv * w.y;
                acc[u4 * 4 + 2] += xv * w.z;
                acc[u4 * 4 + 3] += xv * w.w;
            }
        }
    }

    // e_l / e_r partials, reduce across the 8 col-group lanes
    float sl = 0.f, sr = 0.f;
#pragma unroll
    for (int u = 0; u < 16; ++u) {
        sl += acc[u] * a_l[o0 + u];
        sr += acc[u] * a_r[o0 + u];
    }
#pragma unroll
    for (int off = 4; off; off >>= 1) {
        sl += __shfl_xor(sl, off, 8);
        sr += __shfl_xor(sr, off, 8);
    }
    if (c == 0) {
        el[b * NN + i0 + r] = sl;
        er[b * NN + i0 + r] = sr;
    }

    // ---- transpose tile through LDS, store bf16 hT[b][d][i] ----
    __syncthreads();                  // all waves done reading Ws
    float* hTs = Ws;                  // [128][33] fp32
#pragma unroll
    for (int u = 0; u < 16; ++u) hTs[(o0 + u) * 33 + r] = acc[u];
    __syncthreads();

    {
        int d = t >> 1, half = t & 1;
        const float* src = hTs + d * 33 + half * 16;
        unsigned pk8[8];
#pragma unroll
        for (int k = 0; k < 8; ++k) pk8[k] = pk_bf16(src[2 * k], src[2 * k + 1]);
        unsigned short* dst = hT + ((size_t)(b * DD + d)) * NN + i0 + half * 16;
        *(uint4*)dst       = make_uint4(pk8[0], pk8[1], pk8[2], pk8[3]);
        *(uint4*)(dst + 8) = make_uint4(pk8[4], pk8[5], pk8[6], pk8[7]);
    }
}

// ---------------------------------------------------------------------------
// Kernel B: grid = BB*(NN/16) = 1024 blocks, block = 256 (4 waves).
// Wave w handles j-tiles [w*8, w*8+8) of 32 (each tile = 64 j's).
// Lane within wave: row = lane&15 (score/A row), grp = lane>>4 (k-group).
// A-frag: P[m=lane&15][k=grp*8+u]  (computed in-register, bf16 RTN).
// B-frag: H[k][n] with n=lane&15: 8 contiguous j from hT[b][n0+n][.] (global).
// C/D:    col=lane&15, row=grp*4+reg.
// Per-wave online softmax state (m,l); merged via LDS at the end.
// ---------------------------------------------------------------------------
__global__ __launch_bounds__(256, 4) void attn_kernel(
    const float* __restrict__ x, const int* __restrict__ adj,
    const int* __restrict__ mask, const unsigned short* __restrict__ hT,
    const float* __restrict__ el, const float* __restrict__ er,
    const float* __restrict__ gamma, const float* __restrict__ beta,
    float* __restrict__ outp)
{
    __shared__ __align__(16) float sAcc[4][16][132];  // [wave][row][col(+pad)]
    __shared__ float sM[4][16];
    __shared__ float sL[4][16];

    const int t    = threadIdx.x;
    const int w    = t >> 6;        // wave 0..3
    const int lane = t & 63;
    const int row  = lane & 15;
    const int grp  = lane >> 4;
    const int b    = blockIdx.x >> 7;
    const int it   = blockIdx.x & 127;
    const int i0   = it * 16;
    const int gi   = i0 + row;

    const float el_r = el[b * NN + gi];
    const int   mi   = mask[b * NN + gi];
    const int*  adj_row = adj + ((size_t)(b * NN + gi)) * NN;
    const float* er_b = er + b * NN;
    const int*   mk_b = mask + b * NN;
    const unsigned short* hT_b = hT + (size_t)b * DD * NN;

    f32x4 acc[8];
#pragma unroll
    for (int nb = 0; nb < 8; ++nb) acc[nb] = (f32x4)0.f;
    float m_run = -3.0e38f, l_run = 0.f;

    const int jt_begin = w * (NN / 64 / 4);       // 8 tiles per wave
    const int jt_end   = jt_begin + (NN / 64 / 4);

    // tile-meta prefetch registers (adj, er, mask-j for the 16 j's this lane owns)
    int4 pa0, pa1, pa2, pa3;
    float4 pe0, pe1, pe2, pe3;
    int4 pq0, pq1, pq2, pq3;

    auto load_meta = [&](int jt) {
        const int jb = jt * 64 + grp * 8;
        pa0 = *(const int4*)(adj_row + jb);
        pa1 = *(const int4*)(adj_row + jb + 4);
        pa2 = *(const int4*)(adj_row + jb + 32);
        pa3 = *(const int4*)(adj_row + jb + 36);
        pe0 = *(const float4*)(er_b + jb);
        pe1 = *(const float4*)(er_b + jb + 4);
        pe2 = *(const float4*)(er_b + jb + 32);
        pe3 = *(const float4*)(er_b + jb + 36);
        pq0 = *(const int4*)(mk_b + jb);
        pq1 = *(const int4*)(mk_b + jb + 4);
        pq2 = *(const int4*)(mk_b + jb + 32);
        pq3 = *(const int4*)(mk_b + jb + 36);
    };
    load_meta(jt_begin);

    union BU { int4 q; short8 v; };
    union AU { unsigned u[4]; short8 v; };

#pragma unroll 1
    for (int jt = jt_begin; jt < jt_end; ++jt) {
        // current tile meta
        int4 a0 = pa0, a1 = pa1, a2 = pa2, a3 = pa3;
        float4 e0 = pe0, e1 = pe1, e2 = pe2, e3 = pe3;
        int4 q0 = pq0, q1 = pq1, q2 = pq2, q3 = pq3;
        // prefetch next tile meta (clamped re-load on last iter)
        load_meta(jt < jt_end - 1 ? jt + 1 : jt);

        // B-fragment loads for this tile (16 x 16B from global hT, L2-hot)
        BU bf[16];
        {
            const int jb = jt * 64 + grp * 8;
#pragma unroll
            for (int s = 0; s < 2; ++s)
#pragma unroll
                for (int nb = 0; nb < 8; ++nb)
                    bf[s * 8 + nb].q = *(const int4*)(hT_b
                        + (size_t)(nb * 16 + row) * NN + jb + s * 32);
        }

        // ---- scores for the 16 j's this lane owns ----
        int   av[16] = {a0.x,a0.y,a0.z,a0.w, a1.x,a1.y,a1.z,a1.w,
                        a2.x,a2.y,a2.z,a2.w, a3.x,a3.y,a3.z,a3.w};
        int   qv[16] = {q0.x,q0.y,q0.z,q0.w, q1.x,q1.y,q1.z,q1.w,
                        q2.x,q2.y,q2.z,q2.w, q3.x,q3.y,q3.z,q3.w};
        float ev[16] = {e0.x,e0.y,e0.z,e0.w, e1.x,e1.y,e1.z,e1.w,
                        e2.x,e2.y,e2.z,e2.w, e3.x,e3.y,e3.z,e3.w};
        float ss[16];
        float tmax = -3.0e38f;
#pragma unroll
        for (int u = 0; u < 16; ++u) {
            float e = el_r + ev[u];
            e = fmaxf(e, 0.2f * e);                 // LeakyReLU
            bool ok = (av[u] & qv[u] & mi) != 0;    // adj,mask in {0,1}
            ss[u] = ok ? e : GAT_NEG_INF;
            tmax = fmaxf(tmax, ss[u]);
        }
        tmax = fmaxf(tmax, __shfl_xor(tmax, 16, 64));
        tmax = fmaxf(tmax, __shfl_xor(tmax, 32, 64));
        float m_new = fmaxf(m_run, tmax);
        float al    = __expf(m_run - m_new);
        float p[16];
        float psum = 0.f;
#pragma unroll
        for (int u = 0; u < 16; ++u) {
            p[u] = __expf(ss[u] - m_new);
            psum += p[u];
        }
        psum += __shfl_xor(psum, 16, 64);
        psum += __shfl_xor(psum, 32, 64);
        l_run = l_run * al + psum;
        m_run = m_new;

        // rescale accumulators: C row of element reg is grp*4+reg
        float alr[4];
#pragma unroll
        for (int reg = 0; reg < 4; ++reg) alr[reg] = __shfl(al, grp * 4 + reg, 64);
#pragma unroll
        for (int nb = 0; nb < 8; ++nb) {
            acc[nb][0] *= alr[0]; acc[nb][1] *= alr[1];
            acc[nb][2] *= alr[2]; acc[nb][3] *= alr[3];
        }

        // pack A-fragments (bf16 RTN), k-local order = register element order
        AU A0, A1;
#pragma unroll
        for (int k = 0; k < 4; ++k) {
            A0.u[k] = pk_bf16(p[2 * k],     p[2 * k + 1]);
            A1.u[k] = pk_bf16(p[8 + 2 * k], p[8 + 2 * k + 1]);
        }

        // ---- 16 MFMAs: acc[nb] += P(16x32) @ H(32x16) per kstep ----
#pragma unroll
        for (int nb = 0; nb < 8; ++nb)
            acc[nb] = __builtin_amdgcn_mfma_f32_16x16x32_bf16(A0.v, bf[nb].v, acc[nb], 0, 0, 0);
#pragma unroll
        for (int nb = 0; nb < 8; ++nb)
            acc[nb] = __builtin_amdgcn_mfma_f32_16x16x32_bf16(A1.v, bf[8 + nb].v, acc[nb], 0, 0, 0);
    }

    // ---- write per-wave partial state to LDS ----
#pragma unroll
    for (int nb = 0; nb < 8; ++nb)
#pragma unroll
        for (int reg = 0; reg < 4; ++reg)
            sAcc[w][grp * 4 + reg][nb * 16 + row] = acc[nb][reg];
    if (grp == 0) { sM[w][row] = m_run; sL[w][row] = l_run; }
    __syncthreads();

    // ---- combine (online-softmax merge) + residual + LayerNorm epilogue ----
    // thread t: crow = t>>4 (0..15), cl = t&15; owns cols cl*8 .. cl*8+7
    const int crow = t >> 4;
    const int cl   = t & 15;
    const int gr   = i0 + crow;

    float mw0 = sM[0][crow], mw1 = sM[1][crow], mw2 = sM[2][crow], mw3 = sM[3][crow];
    float M = fmaxf(fmaxf(mw0, mw1), fmaxf(mw2, mw3));
    float sc0 = __expf(mw0 - M), sc1 = __expf(mw1 - M);
    float sc2 = __expf(mw2 - M), sc3 = __expf(mw3 - M);
    float Lsum = sL[0][crow] * sc0 + sL[1][crow] * sc1
               + sL[2][crow] * sc2 + sL[3][crow] * sc3;
    const float linv = 1.0f / Lsum;
    const float mrow = (float)mk_b[gr];
    const float* xrow = x + ((size_t)(b * NN + gr)) * DD;

    float vbuf[8];
    float s1 = 0.f, s2 = 0.f;
#pragma unroll
    for (int h = 0; h < 2; ++h) {
        const int c0 = cl * 8 + h * 4;
        float4 xv = *(const float4*)(xrow + c0);
        float4 a0 = *(const float4*)(&sAcc[0][crow][c0]);
        float4 a1 = *(const float4*)(&sAcc[1][crow][c0]);
        float4 a2 = *(const float4*)(&sAcc[2][crow][c0]);
        float4 a3 = *(const float4*)(&sAcc[3][crow][c0]);
        float tv;
        tv = ((a0.x*sc0 + a1.x*sc1 + a2.x*sc2 + a3.x*sc3) * linv + xv.x) * mrow;
        vbuf[h*4+0] = tv; s1 += tv; s2 += tv*tv;
        tv = ((a0.y*sc0 + a1.y*sc1 + a2.y*sc2 + a3.y*sc3) * linv + xv.y) * mrow;
        vbuf[h*4+1] = tv; s1 += tv; s2 += tv*tv;
        tv = ((a0.z*sc0 + a1.z*sc1 + a2.z*sc2 + a3.z*sc3) * linv + xv.z) * mrow;
        vbuf[h*4+2] = tv; s1 += tv; s2 += tv*tv;
        tv = ((a0.w*sc0 + a1.w*sc1 + a2.w*sc2 + a3.w*sc3) * linv + xv.w) * mrow;
        vbuf[h*4+3] = tv; s1 += tv; s2 += tv*tv;
    }
    // LN reduction across the 16 threads of this crow (lanes differ in bits 0..3)
#pragma unroll
    for (int off = 1; off < 16; off <<= 1) {
        s1 += __shfl_xor(s1, off, 64);
        s2 += __shfl_xor(s2, off, 64);
    }
    const float mu  = s1 * (1.0f / DD);
    const float var = s2 * (1.0f / DD) - mu * mu;
    const float rsd = rsqrtf(var + LN_EPS);

    float* orow = outp + ((size_t)(b * NN + gr)) * DD;
#pragma unroll
    for (int h = 0; h < 2; ++h) {
        const int c0 = cl * 8 + h * 4;
        float4 g  = *(const float4*)(gamma + c0);
        float4 be = *(const float4*)(beta + c0);
        float4 o;
        o.x = (vbuf[h*4+0] - mu) * rsd * g.x + be.x;
        o.y = (vbuf[h*4+1] - mu) * rsd * g.y + be.y;
        o.z = (vbuf[h*4+2] - mu) * rsd * g.z + be.z;
        o.w = (vbuf[h*4+3] - mu) * rsd * g.w + be.w;
        *(float4*)(orow + c0) = o;
    }
}

// ---------------------------------------------------------------------------
extern "C" void kernel_launch(void* const* d_in, const int* in_sizes, int n_in,
                              void* d_out, int out_size, void* d_ws, size_t ws_size,
                              hipStream_t stream) {
    const float* x     = (const float*)d_in[0];
    const int*   adj   = (const int*)d_in[1];
    const int*   maskp = (const int*)d_in[2];
    const float* W     = (const float*)d_in[3];
    const float* a_l   = (const float*)d_in[4];
    const float* a_r   = (const float*)d_in[5];
    const float* gamma = (const float*)d_in[6];
    const float* beta  = (const float*)d_in[7];
    float*       outp  = (float*)d_out;

    // workspace: hT bf16 [B*D*N] (4 MB), e_l, e_r fp32 [B*N]
    unsigned short* hT = (unsigned short*)d_ws;
    float* el = (float*)(hT + (size_t)BB * DD * NN);
    float* er = el + (size_t)BB * NN;

    fc_kernel<<<BB * (NN / 32), 256, 0, stream>>>(x, maskp, W, a_l, a_r, hT, el, er);
    attn_kernel<<<BB * (NN / 16), 256, 0, stream>>>(x, adj, maskp, hT, el, er,
                                                    gamma, beta, outp);
}